// Round 19
// baseline (120.575 us; speedup 1.0000x reference)
//
#include <hip/hip_runtime.h>
#include <math.h>

#define B_  8
#define N_  2048
#define F_  128
#define H1_ 32
#define H2_ 64
#define D1_ 128
#define KS_ 2            // K-split factor for the A-GEMMs
#define KSEG_ (N_ / KS_) // 1024 K per block

typedef unsigned short u16;
typedef unsigned int   u32;
typedef __attribute__((ext_vector_type(8))) short short8;  // 8 bf16 (4 VGPRs)
typedef __attribute__((ext_vector_type(4))) float f32x4;

// ---- round-to-nearest-even fp32 -> bf16, two at a time, packed into u32 ----
__device__ __forceinline__ u32 rne2(float e0, float e1) {
  u32 u0 = __float_as_uint(e0), u1 = __float_as_uint(e1);
  u0 = (u0 + 0x7FFFu + ((u0 >> 16) & 1u)) >> 16;
  u1 = (u1 + 0x7FFFu + ((u1 >> 16) & 1u)) & 0xFFFF0000u;
  return u0 | u1;
}
__device__ __forceinline__ uint4 rne8(const float4 a, const float4 b) {
  return make_uint4(rne2(a.x, a.y), rne2(a.z, a.w), rne2(b.x, b.y), rne2(b.z, b.w));
}

// ---- pack a [64][LDST] fp32 LDS tile (rows = n, cols = h) into MFMA B-frag
// order (bf16 RNE). frag (b, ch, cg): 64 lanes x 8 bf16,
// lane = slot*16+cl holds B[k=cg*32+slot*8+i][col].
template<int H, int LDST>
__device__ __forceinline__ void pack_frags(const float* s, int b, int cgbase,
                                           u16* __restrict__ oh, int tid) {
  constexpr int CGRP = H / 16;
  constexpr int PASSES = H * 8 / 256;
#pragma unroll
  for (int p = 0; p < PASSES; ++p) {
    int q = tid + p * 256;
    int h = q >> 3, nn = (q & 7) * 8;           // 8 consecutive n for col h
    u32 hw[4];
#pragma unroll
    for (int j = 0; j < 4; ++j)
      hw[j] = rne2(s[(nn + 2 * j) * LDST + h], s[(nn + 2 * j + 1) * LDST + h]);
    int ch = h >> 4, cl = h & 15;
    int cg = cgbase + (nn >> 5);
    int lanep = ((nn >> 3) & 3) * 16 + cl;
    size_t o = ((((size_t)b * CGRP + ch) * (N_ / 32) + cg) * 64 + lanep) * 8;
    *(uint4*)(oh + o) = make_uint4(hw[0], hw[1], hw[2], hw[3]);
  }
}

// -------- fused: xw1 = x @ W1 (64-row tile), then pack (bf16) for agemm --------
__global__ __launch_bounds__(256) void k_xw1cvt(const float* __restrict__ x,
                                                const float* __restrict__ W1,
                                                u16* __restrict__ oh) {
  __shared__ float xs[64][F_];        // 32 KB
  __shared__ float w1s[F_ * H1_];     // 16 KB
  __shared__ float s[64][H1_ + 1];    // 8.4 KB
  const int b = blockIdx.y;
  const int n0 = blockIdx.x * 64;
  const int tid = threadIdx.x;
  const float* xp = x + ((size_t)b * N_ + n0) * F_;
#pragma unroll
  for (int i = 0; i < 8; ++i) {       // stage x tile: 8192 floats
    int q = tid + i * 256;
    int r = q >> 5, c4 = (q & 31) * 4;
    *(float4*)&xs[r][c4] = *(const float4*)(xp + (size_t)r * F_ + c4);
  }
#pragma unroll
  for (int i = 0; i < 4; ++i)         // stage W1: 4096 floats
    ((float4*)w1s)[tid + i * 256] = ((const float4*)W1)[tid + i * 256];
  __syncthreads();
  const int r = tid >> 2, c0 = (tid & 3) * 8;
  float acc[8] = {};
#pragma unroll
  for (int k = 0; k < F_; ++k) {
    float xv = xs[r][k];
#pragma unroll
    for (int j = 0; j < 8; ++j)
      acc[j] = fmaf(xv, w1s[k * H1_ + c0 + j], acc[j]);
  }
#pragma unroll
  for (int j = 0; j < 8; ++j) s[r][c0 + j] = acc[j];
  __syncthreads();
  pack_frags<H1_, H1_ + 1>(&s[0][0], b, blockIdx.x * 2, oh, tid);
}

// -------- fused: h1 = relu(sum_z P1 + b1); hw2 = h1 @ W2; pack (bf16) --------
__global__ __launch_bounds__(256) void k_l1fuse(const float* __restrict__ P1,
                                                const float* __restrict__ b1,
                                                const float* __restrict__ W2,
                                                u16* __restrict__ oh) {
  __shared__ float h1s[64][H1_ + 1];   // 8.4 KB
  __shared__ float w2s[H1_ * H2_];     // 8 KB
  __shared__ float hw2s[64][H2_ + 1];  // 16.6 KB
  const int b = blockIdx.y;
  const int n0 = blockIdx.x * 64;
  const int tid = threadIdx.x;
  constexpr size_t TOT = (size_t)B_ * N_ * H1_;   // one z-slice
#pragma unroll
  for (int i = 0; i < 2; ++i) {        // reduce KS partials + bias + relu
    int q = tid + i * 256;
    int r = q >> 3, h4 = (q & 7) * 4;
    size_t base = (((size_t)b * N_) + n0 + r) * H1_ + h4;
    float4 bv = *(const float4*)(b1 + h4);
    float a0 = bv.x, a1 = bv.y, a2 = bv.z, a3 = bv.w;
#pragma unroll
    for (int zz = 0; zz < KS_; ++zz) {
      float4 v = *(const float4*)(P1 + base + (size_t)zz * TOT);
      a0 += v.x; a1 += v.y; a2 += v.z; a3 += v.w;
    }
    h1s[r][h4 + 0] = fmaxf(a0, 0.f);
    h1s[r][h4 + 1] = fmaxf(a1, 0.f);
    h1s[r][h4 + 2] = fmaxf(a2, 0.f);
    h1s[r][h4 + 3] = fmaxf(a3, 0.f);
  }
#pragma unroll
  for (int i = 0; i < 2; ++i)          // stage W2: 2048 floats
    ((float4*)w2s)[tid + i * 256] = ((const float4*)W2)[tid + i * 256];
  __syncthreads();
  const int r = tid >> 2, c0 = (tid & 3) * 16;
  float acc[16] = {};
#pragma unroll
  for (int k = 0; k < H1_; ++k) {
    float hv = h1s[r][k];
#pragma unroll
    for (int j = 0; j < 16; ++j)
      acc[j] = fmaf(hv, w2s[k * H2_ + c0 + j], acc[j]);
  }
#pragma unroll
  for (int j = 0; j < 16; ++j) hw2s[r][c0 + j] = acc[j];
  __syncthreads();
  pack_frags<H2_, H2_ + 1>(&hw2s[0][0], b, blockIdx.x * 2, oh, tid);
}

// -------- MFMA A-GEMM partials: bf16, A+B via LDS, 2-deep pipeline, BK=128 --------
// Grid (N/64, B, KS=2) = 512 blocks x 8 waves (2/CU, 16 waves/CU — unchanged).
// BK=128: NTILE = 8 iterations (HALF of r18) -> per-tile fixed costs (2 barriers
// + vmcnt drain + staging issue) amortized over 2x compute. LDS 50.8/66.8 KB
// (H1/H2) still fits 2 blocks/CU. Same 2-deep named-regset pipeline: issue tile
// t+2, compute tile t, ds_write tile t+1 (counted vmcnt; t+2 stays in flight
// across the barrier).
template<int H>
__global__ __launch_bounds__(512, 4) void k_agemm_mfma(const float* __restrict__ A,
                                                       const u16* __restrict__ Bph,
                                                       float* __restrict__ P) {
  constexpr int NT = H / 16;
  constexpr int NTW = NT / 2;                  // col tiles per wave (H1:1, H2:2)
  constexpr int BK = 128;
  constexpr int CC = BK / 32;                  // 4 chunks per tile
  constexpr int NTILE = KSEG_ / BK;            // 8 (even)
  constexpr int CHSTR = (N_ / 32) * 512;       // u16 stride between colgroups
  constexpr int TOTB = CC * NT * 64;           // B uint4 per tile (H1:512, H2:1024)
  constexpr int BL = TOTB / 512;               // B uint4 loads per thread (1 or 2)
  __shared__ u16 at[2][64][136];               // A tile bf16 (dbuf), 34.8 KB
  __shared__ u16 bt[2][CC][NT][64][8];         // B frags (dbuf): H2 32 KB, H1 16 KB

  const int batch = blockIdx.y;
  const int z = blockIdx.z;
  const int m0 = blockIdx.x * 64;
  const int tid = threadIdx.x;
  const int lane = tid & 63;
  const int wave = tid >> 6;
  const int rg = wave & 3;                     // row-group
  const int cb = (wave >> 2) * NTW;            // col-tile base

  const float* Ab = A + (size_t)batch * N_ * N_ + (size_t)m0 * N_ + (size_t)z * KSEG_;
  const int srow = tid >> 3, sc0 = (tid & 7) * 16;  // A staging: 16 floats/thread

  const int cg0 = z * (KSEG_ / 32);            // first 32-chunk of this K segment
  const u16* Bb = Bph + (size_t)batch * NT * CHSTR;

  // named regsets (A holds even tiles, B holds odd tiles); fixed arrays with
  // compile-time indices after unroll -> registers (rule #20 safe)
  float4 aA[4], aB[4];
  uint4  bA[BL], bB[BL];

#define ISSUE_A(T)                                                              \
  _Pragma("unroll")                                                             \
  for (int i = 0; i < 4; ++i)                                                   \
    aA[i] = *(const float4*)(Ab + (size_t)srow * N_ + (T) * BK + sc0 + 4 * i);  \
  _Pragma("unroll")                                                             \
  for (int i = 0; i < BL; ++i) {                                                \
    int q = tid + i * 512, seg = q >> 6, l2 = q & 63;                           \
    bA[i] = *(const uint4*)(Bb + (size_t)(seg % NT) * CHSTR                     \
              + (size_t)(cg0 + CC * (T) + seg / NT) * 512 + l2 * 8);            \
  }
#define ISSUE_B(T)                                                              \
  _Pragma("unroll")                                                             \
  for (int i = 0; i < 4; ++i)                                                   \
    aB[i] = *(const float4*)(Ab + (size_t)srow * N_ + (T) * BK + sc0 + 4 * i);  \
  _Pragma("unroll")                                                             \
  for (int i = 0; i < BL; ++i) {                                                \
    int q = tid + i * 512, seg = q >> 6, l2 = q & 63;                           \
    bB[i] = *(const uint4*)(Bb + (size_t)(seg % NT) * CHSTR                     \
              + (size_t)(cg0 + CC * (T) + seg / NT) * 512 + l2 * 8);            \
  }
#define WRITE_A(BUF)                                                            \
  *(uint4*)&at[BUF][srow][sc0]     = rne8(aA[0], aA[1]);                        \
  *(uint4*)&at[BUF][srow][sc0 + 8] = rne8(aA[2], aA[3]);                        \
  _Pragma("unroll")                                                             \
  for (int i = 0; i < BL; ++i) {                                                \
    int q = tid + i * 512, seg = q >> 6, l2 = q & 63;                           \
    *(uint4*)&bt[BUF][seg / NT][seg % NT][l2][0] = bA[i];                       \
  }
#define WRITE_B(BUF)                                                            \
  *(uint4*)&at[BUF][srow][sc0]     = rne8(aB[0], aB[1]);                        \
  *(uint4*)&at[BUF][srow][sc0 + 8] = rne8(aB[2], aB[3]);                        \
  _Pragma("unroll")                                                             \
  for (int i = 0; i < BL; ++i) {                                                \
    int q = tid + i * 512, seg = q >> 6, l2 = q & 63;                           \
    *(uint4*)&bt[BUF][seg / NT][seg % NT][l2][0] = bB[i];                       \
  }

  // ---- prologue: tiles 0 (set A) and 1 (set B) in flight; write tile 0 ----
  ISSUE_A(0)
  ISSUE_B(1)
  WRITE_A(0)                                   // counted wait: only set A's loads
  __syncthreads();

  f32x4 acc[NTW];
#pragma unroll
  for (int c = 0; c < NTW; ++c) acc[c] = (f32x4){0.f, 0.f, 0.f, 0.f};

#define COMPUTE(BUF)                                                            \
  _Pragma("unroll")                                                             \
  for (int c = 0; c < CC; ++c) {                                                \
    short8 av = *(const short8*)&at[BUF][rg * 16 + (lane & 15)]                 \
                                  [c * 32 + (lane >> 4) * 8];                   \
    _Pragma("unroll")                                                           \
    for (int j = 0; j < NTW; ++j) {                                             \
      short8 bv = *(const short8*)&bt[BUF][c][cb + j][lane][0];                 \
      acc[j] = __builtin_amdgcn_mfma_f32_16x16x32_bf16(av, bv, acc[j], 0, 0, 0);\
    }                                                                           \
  }

  for (int tt = 0; tt < NTILE; tt += 2) {
    // --- even iteration t = tt: compute buf0; refill set A with tile tt+2 ---
    if (tt + 2 < NTILE) {
      ISSUE_A(tt + 2)
      __builtin_amdgcn_sched_barrier(0);       // pin: loads must not sink
    }
    COMPUTE(0)
    WRITE_B(1)                                 // tile tt+1 (issued last iter)
    __syncthreads();
    // --- odd iteration t = tt+1: compute buf1; refill set B with tile tt+3 ---
    if (tt + 3 < NTILE) {
      ISSUE_B(tt + 3)
      __builtin_amdgcn_sched_barrier(0);
    }
    COMPUTE(1)
    if (tt + 2 < NTILE) {
      WRITE_A(0)                               // tile tt+2 (issued last iter)
    }
    __syncthreads();
  }
#undef ISSUE_A
#undef ISSUE_B
#undef WRITE_A
#undef WRITE_B
#undef COMPUTE

  // C/D layout (m89): col = lane&15, row = (lane>>4)*4 + j
  const int orow = m0 + rg * 16 + ((lane >> 4) << 2);
  float* pp = P + ((size_t)(z * B_ + batch) * N_ + orow) * H + cb * 16 + (lane & 15);
#pragma unroll
  for (int j = 0; j < NTW; ++j)
#pragma unroll
    for (int jj = 0; jj < 4; ++jj)
      pp[(size_t)jj * H + j * 16] = acc[j][jj];
}

// -------- fused: h2 = relu(sum_z P2 + b2); dense partials vs Wd --------
__global__ __launch_bounds__(512) void k_densefuse(const float* __restrict__ P2,
                                                   const float* __restrict__ b2,
                                                   const float* __restrict__ Wd,
                                                   float* __restrict__ part) {
  constexpr int KC = 512;                  // 512 flat elems = 8 n-rows x 64 h
  __shared__ float hs[B_][KC];
  __shared__ float psum[B_][D1_];
  const int kc0 = blockIdx.x * KC;
  const int n0 = blockIdx.x * 8;
  const int tid = threadIdx.x;
  constexpr size_t TOT = (size_t)B_ * N_ * H2_;   // one z-slice
#pragma unroll
  for (int i = 0; i < 2; ++i) {            // reduce KS partials + bias + relu
    int q = tid + i * 512;
    int b = q >> 7, k4 = (q & 127) * 4;
    int nl = k4 >> 6, h = k4 & 63;
    size_t base = (((size_t)b * N_) + n0 + nl) * H2_ + h;
    float4 bv = *(const float4*)(b2 + h);
    float a0 = bv.x, a1 = bv.y, a2 = bv.z, a3 = bv.w;
#pragma unroll
    for (int zz = 0; zz < KS_; ++zz) {
      float4 v = *(const float4*)(P2 + base + (size_t)zz * TOT);
      a0 += v.x; a1 += v.y; a2 += v.z; a3 += v.w;
    }
    hs[b][k4 + 0] = fmaxf(a0, 0.f);
    hs[b][k4 + 1] = fmaxf(a1, 0.f);
    hs[b][k4 + 2] = fmaxf(a2, 0.f);
    hs[b][k4 + 3] = fmaxf(a3, 0.f);
  }
  __syncthreads();
  const int d0 = (tid & 31) * 4;           // 4 output cols
  const int b  = (tid >> 5) & 7;           // batch
  const int ks = tid >> 8;                 // in-block k-split (0/1)
  float a0 = 0.f, a1 = 0.f, a2 = 0.f, a3 = 0.f;
  const float* wp = Wd + ((size_t)kc0 + ks * 256) * D1_ + d0;
  const float* hp = &hs[b][ks * 256];
#pragma unroll 4
  for (int k = 0; k < 256; ++k) {
    float4 w = *(const float4*)(wp + (size_t)k * D1_);
    float h = hp[k];
    a0 = fmaf(h, w.x, a0); a1 = fmaf(h, w.y, a1);
    a2 = fmaf(h, w.z, a2); a3 = fmaf(h, w.w, a3);
  }
  if (ks == 1) {
    psum[b][d0] = a0; psum[b][d0 + 1] = a1; psum[b][d0 + 2] = a2; psum[b][d0 + 3] = a3;
  }
  __syncthreads();
  if (ks == 0) {
    float* pp = part + ((size_t)blockIdx.x * B_ + b) * D1_ + d0;
    *(float4*)pp = make_float4(a0 + psum[b][d0], a1 + psum[b][d0 + 1],
                               a2 + psum[b][d0 + 2], a3 + psum[b][d0 + 3]);
  }
}

// -------- final: per-batch block reduces 256 dense partials + sigmoid --------
__global__ __launch_bounds__(512) void k_dense_final(const float* __restrict__ part,
                                                     const float* __restrict__ bd,
                                                     const float* __restrict__ Wo,
                                                     const float* __restrict__ bo,
                                                     float* __restrict__ out) {
  __shared__ float ps[512];
  __shared__ float hdv[D1_];
  const int b = blockIdx.x;
  const int tid = threadIdx.x;
  const int d = tid & 127, seg = tid >> 7;     // 4-way k-split over 256 chunks
  float s = 0.f;
  for (int i = seg * 64; i < seg * 64 + 64; ++i)
    s += part[(size_t)i * (B_ * D1_) + b * D1_ + d];
  ps[tid] = s;
  __syncthreads();
  if (seg == 0)
    hdv[d] = fmaxf(ps[d] + ps[128 + d] + ps[256 + d] + ps[384 + d] + bd[d], 0.f);
  __syncthreads();
  if (tid < 64) {
    float v = hdv[tid] * Wo[tid] + hdv[64 + tid] * Wo[64 + tid];
#pragma unroll
    for (int off = 32; off; off >>= 1) v += __shfl_down(v, off, 64);
    if (tid == 0) out[b] = 1.f / (1.f + expf(-(v + bo[0])));
  }
}

extern "C" void kernel_launch(void* const* d_in, const int* in_sizes, int n_in,
                              void* d_out, int out_size, void* d_ws, size_t ws_size,
                              hipStream_t stream) {
  const float* x  = (const float*)d_in[0];
  const float* a  = (const float*)d_in[1];
  const float* W1 = (const float*)d_in[2];
  const float* b1 = (const float*)d_in[3];
  const float* W2 = (const float*)d_in[4];
  const float* b2 = (const float*)d_in[5];
  const float* Wd = (const float*)d_in[6];
  const float* bd = (const float*)d_in[7];
  const float* Wo = (const float*)d_in[8];
  const float* bo = (const float*)d_in[9];
  float* out = (float*)d_out;

  // workspace (floats): total 3,145,728 floats = 12.6 MB
  //  [0, 2097152)          P: agemm partials KS=2 (H1 uses first 1M, H2 all 2M)
  //  [2097152, 2359296)    Bt1h (bf16, 512K u16)
  //  [2359296, 2883584)    Bt2h (bf16, 1M u16)
  //  [2883584, 3145728)    dpart (256*8*128)
  float* ws    = (float*)d_ws;
  float* P     = ws;
  u16*   Bt1h  = (u16*)(ws + 2097152);
  u16*   Bt2h  = (u16*)(ws + 2359296);
  float* dpart = ws + 2883584;

  k_xw1cvt<<<dim3(N_ / 64, B_), 256, 0, stream>>>(x, W1, Bt1h);
  k_agemm_mfma<H1_><<<dim3(N_ / 64, B_, KS_), 512, 0, stream>>>(a, Bt1h, P);
  k_l1fuse<<<dim3(N_ / 64, B_), 256, 0, stream>>>(P, b1, W2, Bt2h);
  k_agemm_mfma<H2_><<<dim3(N_ / 64, B_, KS_), 512, 0, stream>>>(a, Bt2h, P);
  k_densefuse<<<(N_ * H2_) / 512, 512, 0, stream>>>(P, b2, Wd, dpart);
  k_dense_final<<<B_, 512, 0, stream>>>(dpart, bd, Wo, bo, out);
}

// Round 20
// 103.650 us; speedup vs baseline: 1.1633x; 1.1633x over previous
//
#include <hip/hip_runtime.h>
#include <math.h>

#define B_  8
#define N_  2048
#define F_  128
#define H1_ 32
#define H2_ 64
#define D1_ 128
#define KS_ 2            // K-split factor for the A-GEMMs
#define KSEG_ (N_ / KS_) // 1024 K per block

typedef unsigned short u16;
typedef unsigned int   u32;
typedef __attribute__((ext_vector_type(8))) short short8;  // 8 bf16 (4 VGPRs)
typedef __attribute__((ext_vector_type(4))) float f32x4;

// ---- round-to-nearest-even fp32 -> bf16, two at a time, packed into u32 ----
__device__ __forceinline__ u32 rne2(float e0, float e1) {
  u32 u0 = __float_as_uint(e0), u1 = __float_as_uint(e1);
  u0 = (u0 + 0x7FFFu + ((u0 >> 16) & 1u)) >> 16;
  u1 = (u1 + 0x7FFFu + ((u1 >> 16) & 1u)) & 0xFFFF0000u;
  return u0 | u1;
}
__device__ __forceinline__ uint4 rne8(const float4 a, const float4 b) {
  return make_uint4(rne2(a.x, a.y), rne2(a.z, a.w), rne2(b.x, b.y), rne2(b.z, b.w));
}

// ---- pack a [64][LDST] fp32 LDS tile (rows = n, cols = h) into MFMA B-frag
// order (bf16 RNE). frag (b, ch, cg): 64 lanes x 8 bf16,
// lane = slot*16+cl holds B[k=cg*32+slot*8+i][col].
template<int H, int LDST>
__device__ __forceinline__ void pack_frags(const float* s, int b, int cgbase,
                                           u16* __restrict__ oh, int tid) {
  constexpr int CGRP = H / 16;
  constexpr int PASSES = H * 8 / 256;
#pragma unroll
  for (int p = 0; p < PASSES; ++p) {
    int q = tid + p * 256;
    int h = q >> 3, nn = (q & 7) * 8;           // 8 consecutive n for col h
    u32 hw[4];
#pragma unroll
    for (int j = 0; j < 4; ++j)
      hw[j] = rne2(s[(nn + 2 * j) * LDST + h], s[(nn + 2 * j + 1) * LDST + h]);
    int ch = h >> 4, cl = h & 15;
    int cg = cgbase + (nn >> 5);
    int lanep = ((nn >> 3) & 3) * 16 + cl;
    size_t o = ((((size_t)b * CGRP + ch) * (N_ / 32) + cg) * 64 + lanep) * 8;
    *(uint4*)(oh + o) = make_uint4(hw[0], hw[1], hw[2], hw[3]);
  }
}

// -------- fused: xw1 = x @ W1 (64-row tile), then pack (bf16) for agemm --------
__global__ __launch_bounds__(256) void k_xw1cvt(const float* __restrict__ x,
                                                const float* __restrict__ W1,
                                                u16* __restrict__ oh) {
  __shared__ float xs[64][F_];        // 32 KB
  __shared__ float w1s[F_ * H1_];     // 16 KB
  __shared__ float s[64][H1_ + 1];    // 8.4 KB
  const int b = blockIdx.y;
  const int n0 = blockIdx.x * 64;
  const int tid = threadIdx.x;
  const float* xp = x + ((size_t)b * N_ + n0) * F_;
#pragma unroll
  for (int i = 0; i < 8; ++i) {       // stage x tile: 8192 floats
    int q = tid + i * 256;
    int r = q >> 5, c4 = (q & 31) * 4;
    *(float4*)&xs[r][c4] = *(const float4*)(xp + (size_t)r * F_ + c4);
  }
#pragma unroll
  for (int i = 0; i < 4; ++i)         // stage W1: 4096 floats
    ((float4*)w1s)[tid + i * 256] = ((const float4*)W1)[tid + i * 256];
  __syncthreads();
  const int r = tid >> 2, c0 = (tid & 3) * 8;
  float acc[8] = {};
#pragma unroll
  for (int k = 0; k < F_; ++k) {
    float xv = xs[r][k];
#pragma unroll
    for (int j = 0; j < 8; ++j)
      acc[j] = fmaf(xv, w1s[k * H1_ + c0 + j], acc[j]);
  }
#pragma unroll
  for (int j = 0; j < 8; ++j) s[r][c0 + j] = acc[j];
  __syncthreads();
  pack_frags<H1_, H1_ + 1>(&s[0][0], b, blockIdx.x * 2, oh, tid);
}

// -------- fused: h1 = relu(sum_z P1 + b1); hw2 = h1 @ W2; pack (bf16) --------
__global__ __launch_bounds__(256) void k_l1fuse(const float* __restrict__ P1,
                                                const float* __restrict__ b1,
                                                const float* __restrict__ W2,
                                                u16* __restrict__ oh) {
  __shared__ float h1s[64][H1_ + 1];   // 8.4 KB
  __shared__ float w2s[H1_ * H2_];     // 8 KB
  __shared__ float hw2s[64][H2_ + 1];  // 16.6 KB
  const int b = blockIdx.y;
  const int n0 = blockIdx.x * 64;
  const int tid = threadIdx.x;
  constexpr size_t TOT = (size_t)B_ * N_ * H1_;   // one z-slice
#pragma unroll
  for (int i = 0; i < 2; ++i) {        // reduce KS partials + bias + relu
    int q = tid + i * 256;
    int r = q >> 3, h4 = (q & 7) * 4;
    size_t base = (((size_t)b * N_) + n0 + r) * H1_ + h4;
    float4 bv = *(const float4*)(b1 + h4);
    float a0 = bv.x, a1 = bv.y, a2 = bv.z, a3 = bv.w;
#pragma unroll
    for (int zz = 0; zz < KS_; ++zz) {
      float4 v = *(const float4*)(P1 + base + (size_t)zz * TOT);
      a0 += v.x; a1 += v.y; a2 += v.z; a3 += v.w;
    }
    h1s[r][h4 + 0] = fmaxf(a0, 0.f);
    h1s[r][h4 + 1] = fmaxf(a1, 0.f);
    h1s[r][h4 + 2] = fmaxf(a2, 0.f);
    h1s[r][h4 + 3] = fmaxf(a3, 0.f);
  }
#pragma unroll
  for (int i = 0; i < 2; ++i)          // stage W2: 2048 floats
    ((float4*)w2s)[tid + i * 256] = ((const float4*)W2)[tid + i * 256];
  __syncthreads();
  const int r = tid >> 2, c0 = (tid & 3) * 16;
  float acc[16] = {};
#pragma unroll
  for (int k = 0; k < H1_; ++k) {
    float hv = h1s[r][k];
#pragma unroll
    for (int j = 0; j < 16; ++j)
      acc[j] = fmaf(hv, w2s[k * H2_ + c0 + j], acc[j]);
  }
#pragma unroll
  for (int j = 0; j < 16; ++j) hw2s[r][c0 + j] = acc[j];
  __syncthreads();
  pack_frags<H2_, H2_ + 1>(&hw2s[0][0], b, blockIdx.x * 2, oh, tid);
}

// -------- MFMA A-GEMM partials: bf16, A+B via LDS, 2-deep pipeline, KS=2 --------
// Grid (N/64, B, KS=2) = 512 blocks x 8 waves (2/CU -> 16 waves/CU).
// Iteration t: issue tile t+2 loads (named regset, pinned by sched_barrier);
// compute tile t from LDS; ds_write tile t+1's regs (counted vmcnt wait,
// t+2's loads stay in flight ACROSS the barrier). Best-measured config (r18).
template<int H>
__global__ __launch_bounds__(512, 8) void k_agemm_mfma(const float* __restrict__ A,
                                                       const u16* __restrict__ Bph,
                                                       float* __restrict__ P) {
  constexpr int NT = H / 16;
  constexpr int NTW = NT / 2;                  // col tiles per wave (H1:1, H2:2)
  constexpr int BK = 64;
  constexpr int NTILE = KSEG_ / BK;            // 16 (even)
  constexpr int CHSTR = (N_ / 32) * 512;       // u16 stride between colgroups
  constexpr int TOTB = 2 * NT * 64;            // B uint4 per tile (H1:256, H2:512)
  __shared__ u16 at[2][64][72];                // A tile bf16 (dbuf), 18.4 KB
  __shared__ u16 bt[2][2][NT][64][8];          // B frags (dbuf): H2 16 KB, H1 8 KB

  const int batch = blockIdx.y;
  const int z = blockIdx.z;
  const int m0 = blockIdx.x * 64;
  const int tid = threadIdx.x;
  const int lane = tid & 63;
  const int wave = tid >> 6;
  const int rg = wave & 3;                     // row-group
  const int cb = (wave >> 2) * NTW;            // col-tile base

  const float* Ab = A + (size_t)batch * N_ * N_ + (size_t)m0 * N_ + (size_t)z * KSEG_;
  const int srow = tid >> 3, sc0 = (tid & 7) * 8;   // A staging: eighth-row each

  const int cg0 = z * (KSEG_ / 32);            // first 32-chunk of this K segment
  const u16* Bb = Bph + (size_t)batch * NT * CHSTR;
  const int bseg = tid >> 6, bl2 = tid & 63;
  const int bcc = bseg / NT, bch = bseg % NT;  // valid when tid < TOTB

  // named regsets (A holds even tiles, B holds odd tiles)
  float4 aA0, aA1, aB0, aB1;
  uint4  sbA, sbB;

#define ISSUE_A(T)                                                              \
  aA0 = *(const float4*)(Ab + (size_t)srow * N_ + (T) * BK + sc0);              \
  aA1 = *(const float4*)(Ab + (size_t)srow * N_ + (T) * BK + sc0 + 4);          \
  if (tid < TOTB) sbA = *(const uint4*)(Bb + (size_t)bch * CHSTR                \
                          + (size_t)(cg0 + 2 * (T) + bcc) * 512 + bl2 * 8);
#define ISSUE_B(T)                                                              \
  aB0 = *(const float4*)(Ab + (size_t)srow * N_ + (T) * BK + sc0);              \
  aB1 = *(const float4*)(Ab + (size_t)srow * N_ + (T) * BK + sc0 + 4);          \
  if (tid < TOTB) sbB = *(const uint4*)(Bb + (size_t)bch * CHSTR                \
                          + (size_t)(cg0 + 2 * (T) + bcc) * 512 + bl2 * 8);
#define WRITE_A(BUF)                                                            \
  *(uint4*)&at[BUF][srow][sc0] = rne8(aA0, aA1);                                \
  if (tid < TOTB) *(uint4*)&bt[BUF][bcc][bch][bl2][0] = sbA;
#define WRITE_B(BUF)                                                            \
  *(uint4*)&at[BUF][srow][sc0] = rne8(aB0, aB1);                                \
  if (tid < TOTB) *(uint4*)&bt[BUF][bcc][bch][bl2][0] = sbB;

  // ---- prologue: tiles 0 (set A) and 1 (set B) in flight; write tile 0 ----
  ISSUE_A(0)
  ISSUE_B(1)
  WRITE_A(0)                                   // counted wait: only set A's loads
  __syncthreads();

  f32x4 acc[NTW];
#pragma unroll
  for (int c = 0; c < NTW; ++c) acc[c] = (f32x4){0.f, 0.f, 0.f, 0.f};

#define COMPUTE(BUF)                                                            \
  _Pragma("unroll")                                                             \
  for (int c = 0; c < 2; ++c) {                                                 \
    short8 av = *(const short8*)&at[BUF][rg * 16 + (lane & 15)]                 \
                                  [c * 32 + (lane >> 4) * 8];                   \
    _Pragma("unroll")                                                           \
    for (int j = 0; j < NTW; ++j) {                                             \
      short8 bv = *(const short8*)&bt[BUF][c][cb + j][lane][0];                 \
      acc[j] = __builtin_amdgcn_mfma_f32_16x16x32_bf16(av, bv, acc[j], 0, 0, 0);\
    }                                                                           \
  }

  for (int tt = 0; tt < NTILE; tt += 2) {
    // --- even iteration t = tt: compute buf0; refill set A with tile tt+2 ---
    if (tt + 2 < NTILE) {
      ISSUE_A(tt + 2)
      __builtin_amdgcn_sched_barrier(0);       // pin: loads must not sink
    }
    COMPUTE(0)
    WRITE_B(1)                                 // tile tt+1 (issued last iter)
    __syncthreads();
    // --- odd iteration t = tt+1: compute buf1; refill set B with tile tt+3 ---
    if (tt + 3 < NTILE) {
      ISSUE_B(tt + 3)
      __builtin_amdgcn_sched_barrier(0);
    }
    COMPUTE(1)
    if (tt + 2 < NTILE) {
      WRITE_A(0)                               // tile tt+2 (issued last iter)
    }
    __syncthreads();
  }
#undef ISSUE_A
#undef ISSUE_B
#undef WRITE_A
#undef WRITE_B
#undef COMPUTE

  // C/D layout (m89): col = lane&15, row = (lane>>4)*4 + j
  const int orow = m0 + rg * 16 + ((lane >> 4) << 2);
  float* pp = P + ((size_t)(z * B_ + batch) * N_ + orow) * H + cb * 16 + (lane & 15);
#pragma unroll
  for (int j = 0; j < NTW; ++j)
#pragma unroll
    for (int jj = 0; jj < 4; ++jj)
      pp[(size_t)jj * H + j * 16] = acc[j][jj];
}

// -------- fused: h2 = relu(sum_z P2 + b2); dense partials vs Wd --------
__global__ __launch_bounds__(512) void k_densefuse(const float* __restrict__ P2,
                                                   const float* __restrict__ b2,
                                                   const float* __restrict__ Wd,
                                                   float* __restrict__ part) {
  constexpr int KC = 512;                  // 512 flat elems = 8 n-rows x 64 h
  __shared__ float hs[B_][KC];
  __shared__ float psum[B_][D1_];
  const int kc0 = blockIdx.x * KC;
  const int n0 = blockIdx.x * 8;
  const int tid = threadIdx.x;
  constexpr size_t TOT = (size_t)B_ * N_ * H2_;   // one z-slice
#pragma unroll
  for (int i = 0; i < 2; ++i) {            // reduce KS partials + bias + relu
    int q = tid + i * 512;
    int b = q >> 7, k4 = (q & 127) * 4;
    int nl = k4 >> 6, h = k4 & 63;
    size_t base = (((size_t)b * N_) + n0 + nl) * H2_ + h;
    float4 bv = *(const float4*)(b2 + h);
    float a0 = bv.x, a1 = bv.y, a2 = bv.z, a3 = bv.w;
#pragma unroll
    for (int zz = 0; zz < KS_; ++zz) {
      float4 v = *(const float4*)(P2 + base + (size_t)zz * TOT);
      a0 += v.x; a1 += v.y; a2 += v.z; a3 += v.w;
    }
    hs[b][k4 + 0] = fmaxf(a0, 0.f);
    hs[b][k4 + 1] = fmaxf(a1, 0.f);
    hs[b][k4 + 2] = fmaxf(a2, 0.f);
    hs[b][k4 + 3] = fmaxf(a3, 0.f);
  }
  __syncthreads();
  const int d0 = (tid & 31) * 4;           // 4 output cols
  const int b  = (tid >> 5) & 7;           // batch
  const int ks = tid >> 8;                 // in-block k-split (0/1)
  float a0 = 0.f, a1 = 0.f, a2 = 0.f, a3 = 0.f;
  const float* wp = Wd + ((size_t)kc0 + ks * 256) * D1_ + d0;
  const float* hp = &hs[b][ks * 256];
#pragma unroll 4
  for (int k = 0; k < 256; ++k) {
    float4 w = *(const float4*)(wp + (size_t)k * D1_);
    float h = hp[k];
    a0 = fmaf(h, w.x, a0); a1 = fmaf(h, w.y, a1);
    a2 = fmaf(h, w.z, a2); a3 = fmaf(h, w.w, a3);
  }
  if (ks == 1) {
    psum[b][d0] = a0; psum[b][d0 + 1] = a1; psum[b][d0 + 2] = a2; psum[b][d0 + 3] = a3;
  }
  __syncthreads();
  if (ks == 0) {
    float* pp = part + ((size_t)blockIdx.x * B_ + b) * D1_ + d0;
    *(float4*)pp = make_float4(a0 + psum[b][d0], a1 + psum[b][d0 + 1],
                               a2 + psum[b][d0 + 2], a3 + psum[b][d0 + 3]);
  }
}

// -------- final: per-batch block reduces 256 dense partials + sigmoid --------
__global__ __launch_bounds__(512) void k_dense_final(const float* __restrict__ part,
                                                     const float* __restrict__ bd,
                                                     const float* __restrict__ Wo,
                                                     const float* __restrict__ bo,
                                                     float* __restrict__ out) {
  __shared__ float ps[512];
  __shared__ float hdv[D1_];
  const int b = blockIdx.x;
  const int tid = threadIdx.x;
  const int d = tid & 127, seg = tid >> 7;     // 4-way k-split over 256 chunks
  float s = 0.f;
  for (int i = seg * 64; i < seg * 64 + 64; ++i)
    s += part[(size_t)i * (B_ * D1_) + b * D1_ + d];
  ps[tid] = s;
  __syncthreads();
  if (seg == 0)
    hdv[d] = fmaxf(ps[d] + ps[128 + d] + ps[256 + d] + ps[384 + d] + bd[d], 0.f);
  __syncthreads();
  if (tid < 64) {
    float v = hdv[tid] * Wo[tid] + hdv[64 + tid] * Wo[64 + tid];
#pragma unroll
    for (int off = 32; off; off >>= 1) v += __shfl_down(v, off, 64);
    if (tid == 0) out[b] = 1.f / (1.f + expf(-(v + bo[0])));
  }
}

extern "C" void kernel_launch(void* const* d_in, const int* in_sizes, int n_in,
                              void* d_out, int out_size, void* d_ws, size_t ws_size,
                              hipStream_t stream) {
  const float* x  = (const float*)d_in[0];
  const float* a  = (const float*)d_in[1];
  const float* W1 = (const float*)d_in[2];
  const float* b1 = (const float*)d_in[3];
  const float* W2 = (const float*)d_in[4];
  const float* b2 = (const float*)d_in[5];
  const float* Wd = (const float*)d_in[6];
  const float* bd = (const float*)d_in[7];
  const float* Wo = (const float*)d_in[8];
  const float* bo = (const float*)d_in[9];
  float* out = (float*)d_out;

  // workspace (floats): total 3,145,728 floats = 12.6 MB
  //  [0, 2097152)          P: agemm partials KS=2 (H1 uses first 1M, H2 all 2M)
  //  [2097152, 2359296)    Bt1h (bf16, 512K u16)
  //  [2359296, 2883584)    Bt2h (bf16, 1M u16)
  //  [2883584, 3145728)    dpart (256*8*128)
  float* ws    = (float*)d_ws;
  float* P     = ws;
  u16*   Bt1h  = (u16*)(ws + 2097152);
  u16*   Bt2h  = (u16*)(ws + 2359296);
  float* dpart = ws + 2883584;

  k_xw1cvt<<<dim3(N_ / 64, B_), 256, 0, stream>>>(x, W1, Bt1h);
  k_agemm_mfma<H1_><<<dim3(N_ / 64, B_, KS_), 512, 0, stream>>>(a, Bt1h, P);
  k_l1fuse<<<dim3(N_ / 64, B_), 256, 0, stream>>>(P, b1, W2, Bt2h);
  k_agemm_mfma<H2_><<<dim3(N_ / 64, B_, KS_), 512, 0, stream>>>(a, Bt2h, P);
  k_densefuse<<<(N_ * H2_) / 512, 512, 0, stream>>>(P, b2, Wd, dpart);
  k_dense_final<<<B_, 512, 0, stream>>>(dpart, bd, Wo, bo, out);
}

// Round 21
// 98.413 us; speedup vs baseline: 1.2252x; 1.0532x over previous
//
#include <hip/hip_runtime.h>
#include <math.h>

#define B_  8
#define N_  2048
#define F_  128
#define H1_ 32
#define H2_ 64
#define D1_ 128
#define KS_ 2            // K-split factor for the A-GEMMs
#define KSEG_ (N_ / KS_) // 1024 K per block

typedef unsigned short u16;
typedef unsigned int   u32;
typedef __attribute__((ext_vector_type(8))) short short8;  // 8 bf16 (4 VGPRs)
typedef __attribute__((ext_vector_type(4))) float f32x4;

// ---- round-to-nearest-even fp32 -> bf16, two at a time, packed into u32 ----
__device__ __forceinline__ u32 rne2(float e0, float e1) {
  u32 u0 = __float_as_uint(e0), u1 = __float_as_uint(e1);
  u0 = (u0 + 0x7FFFu + ((u0 >> 16) & 1u)) >> 16;
  u1 = (u1 + 0x7FFFu + ((u1 >> 16) & 1u)) & 0xFFFF0000u;
  return u0 | u1;
}
__device__ __forceinline__ uint4 rne8(const float4 a, const float4 b) {
  return make_uint4(rne2(a.x, a.y), rne2(a.z, a.w), rne2(b.x, b.y), rne2(b.z, b.w));
}

// ---- pack a [64][LDST] fp32 LDS tile (rows = n, cols = h) into MFMA B-frag
// order (bf16 RNE). frag (b, ch, cg): 64 lanes x 8 bf16,
// lane = slot*16+cl holds B[k=cg*32+slot*8+i][col].
template<int H, int LDST>
__device__ __forceinline__ void pack_frags(const float* s, int b, int cgbase,
                                           u16* __restrict__ oh, int tid) {
  constexpr int CGRP = H / 16;
  constexpr int PASSES = H * 8 / 256;
#pragma unroll
  for (int p = 0; p < PASSES; ++p) {
    int q = tid + p * 256;
    int h = q >> 3, nn = (q & 7) * 8;           // 8 consecutive n for col h
    u32 hw[4];
#pragma unroll
    for (int j = 0; j < 4; ++j)
      hw[j] = rne2(s[(nn + 2 * j) * LDST + h], s[(nn + 2 * j + 1) * LDST + h]);
    int ch = h >> 4, cl = h & 15;
    int cg = cgbase + (nn >> 5);
    int lanep = ((nn >> 3) & 3) * 16 + cl;
    size_t o = ((((size_t)b * CGRP + ch) * (N_ / 32) + cg) * 64 + lanep) * 8;
    *(uint4*)(oh + o) = make_uint4(hw[0], hw[1], hw[2], hw[3]);
  }
}

// -------- fused: xw1 = x @ W1 (64-row tile), then pack (bf16) for agemm --------
__global__ __launch_bounds__(256) void k_xw1cvt(const float* __restrict__ x,
                                                const float* __restrict__ W1,
                                                u16* __restrict__ oh) {
  __shared__ float xs[64][F_];        // 32 KB
  __shared__ float w1s[F_ * H1_];     // 16 KB
  __shared__ float s[64][H1_ + 1];    // 8.4 KB
  const int b = blockIdx.y;
  const int n0 = blockIdx.x * 64;
  const int tid = threadIdx.x;
  const float* xp = x + ((size_t)b * N_ + n0) * F_;
#pragma unroll
  for (int i = 0; i < 8; ++i) {       // stage x tile: 8192 floats
    int q = tid + i * 256;
    int r = q >> 5, c4 = (q & 31) * 4;
    *(float4*)&xs[r][c4] = *(const float4*)(xp + (size_t)r * F_ + c4);
  }
#pragma unroll
  for (int i = 0; i < 4; ++i)         // stage W1: 4096 floats
    ((float4*)w1s)[tid + i * 256] = ((const float4*)W1)[tid + i * 256];
  __syncthreads();
  const int r = tid >> 2, c0 = (tid & 3) * 8;
  float acc[8] = {};
#pragma unroll
  for (int k = 0; k < F_; ++k) {
    float xv = xs[r][k];
#pragma unroll
    for (int j = 0; j < 8; ++j)
      acc[j] = fmaf(xv, w1s[k * H1_ + c0 + j], acc[j]);
  }
#pragma unroll
  for (int j = 0; j < 8; ++j) s[r][c0 + j] = acc[j];
  __syncthreads();
  pack_frags<H1_, H1_ + 1>(&s[0][0], b, blockIdx.x * 2, oh, tid);
}

// -------- fused: h1 = relu(sum_z P1 + b1); hw2 = h1 @ W2; pack (bf16) --------
__global__ __launch_bounds__(256) void k_l1fuse(const float* __restrict__ P1,
                                                const float* __restrict__ b1,
                                                const float* __restrict__ W2,
                                                u16* __restrict__ oh) {
  __shared__ float h1s[64][H1_ + 1];   // 8.4 KB
  __shared__ float w2s[H1_ * H2_];     // 8 KB
  __shared__ float hw2s[64][H2_ + 1];  // 16.6 KB
  const int b = blockIdx.y;
  const int n0 = blockIdx.x * 64;
  const int tid = threadIdx.x;
  constexpr size_t TOT = (size_t)B_ * N_ * H1_;   // one z-slice
#pragma unroll
  for (int i = 0; i < 2; ++i) {        // reduce KS partials + bias + relu
    int q = tid + i * 256;
    int r = q >> 3, h4 = (q & 7) * 4;
    size_t base = (((size_t)b * N_) + n0 + r) * H1_ + h4;
    float4 bv = *(const float4*)(b1 + h4);
    float a0 = bv.x, a1 = bv.y, a2 = bv.z, a3 = bv.w;
#pragma unroll
    for (int zz = 0; zz < KS_; ++zz) {
      float4 v = *(const float4*)(P1 + base + (size_t)zz * TOT);
      a0 += v.x; a1 += v.y; a2 += v.z; a3 += v.w;
    }
    h1s[r][h4 + 0] = fmaxf(a0, 0.f);
    h1s[r][h4 + 1] = fmaxf(a1, 0.f);
    h1s[r][h4 + 2] = fmaxf(a2, 0.f);
    h1s[r][h4 + 3] = fmaxf(a3, 0.f);
  }
#pragma unroll
  for (int i = 0; i < 2; ++i)          // stage W2: 2048 floats
    ((float4*)w2s)[tid + i * 256] = ((const float4*)W2)[tid + i * 256];
  __syncthreads();
  const int r = tid >> 2, c0 = (tid & 3) * 16;
  float acc[16] = {};
#pragma unroll
  for (int k = 0; k < H1_; ++k) {
    float hv = h1s[r][k];
#pragma unroll
    for (int j = 0; j < 16; ++j)
      acc[j] = fmaf(hv, w2s[k * H2_ + c0 + j], acc[j]);
  }
#pragma unroll
  for (int j = 0; j < 16; ++j) hw2s[r][c0 + j] = acc[j];
  __syncthreads();
  pack_frags<H2_, H2_ + 1>(&hw2s[0][0], b, blockIdx.x * 2, oh, tid);
}

// -------- MFMA A-GEMM partials: bf16, A+B via LDS, 2-deep pipeline, KS=2 --------
// 1D grid 512 blocks x 8 waves with XCD-AWARE SWIZZLE (T1): block i is assigned
// work swz = (i%8)*64 + i/8 (bijective, 512%8==0), so each XCD's 64 blocks get
// a contiguous chunk = 2 full batches at one z -> its L2 holds just 2 B panels
// (256 KB resident) and streams contiguous A rows. Decode (m0,batch,z) from swz.
// Everything else identical to the best-measured r18/r20 config.
template<int H>
__global__ __launch_bounds__(512, 8) void k_agemm_mfma(const float* __restrict__ A,
                                                       const u16* __restrict__ Bph,
                                                       float* __restrict__ P) {
  constexpr int NT = H / 16;
  constexpr int NTW = NT / 2;                  // col tiles per wave (H1:1, H2:2)
  constexpr int BK = 64;
  constexpr int NTILE = KSEG_ / BK;            // 16 (even)
  constexpr int CHSTR = (N_ / 32) * 512;       // u16 stride between colgroups
  constexpr int TOTB = 2 * NT * 64;            // B uint4 per tile (H1:256, H2:512)
  constexpr int NWG = (N_ / 64) * B_ * KS_;    // 512
  __shared__ u16 at[2][64][72];                // A tile bf16 (dbuf), 18.4 KB
  __shared__ u16 bt[2][2][NT][64][8];          // B frags (dbuf): H2 16 KB, H1 8 KB

  // XCD-aware bijective swizzle: same-XCD blocks take contiguous work ids
  const int swz = (blockIdx.x & 7) * (NWG >> 3) + (blockIdx.x >> 3);
  const int m0 = (swz & 31) * 64;              // m-tile (fastest)
  const int batch = (swz >> 5) & 7;
  const int z = swz >> 8;

  const int tid = threadIdx.x;
  const int lane = tid & 63;
  const int wave = tid >> 6;
  const int rg = wave & 3;                     // row-group
  const int cb = (wave >> 2) * NTW;            // col-tile base

  const float* Ab = A + (size_t)batch * N_ * N_ + (size_t)m0 * N_ + (size_t)z * KSEG_;
  const int srow = tid >> 3, sc0 = (tid & 7) * 8;   // A staging: eighth-row each

  const int cg0 = z * (KSEG_ / 32);            // first 32-chunk of this K segment
  const u16* Bb = Bph + (size_t)batch * NT * CHSTR;
  const int bseg = tid >> 6, bl2 = tid & 63;
  const int bcc = bseg / NT, bch = bseg % NT;  // valid when tid < TOTB

  // named regsets (A holds even tiles, B holds odd tiles)
  float4 aA0, aA1, aB0, aB1;
  uint4  sbA, sbB;

#define ISSUE_A(T)                                                              \
  aA0 = *(const float4*)(Ab + (size_t)srow * N_ + (T) * BK + sc0);              \
  aA1 = *(const float4*)(Ab + (size_t)srow * N_ + (T) * BK + sc0 + 4);          \
  if (tid < TOTB) sbA = *(const uint4*)(Bb + (size_t)bch * CHSTR                \
                          + (size_t)(cg0 + 2 * (T) + bcc) * 512 + bl2 * 8);
#define ISSUE_B(T)                                                              \
  aB0 = *(const float4*)(Ab + (size_t)srow * N_ + (T) * BK + sc0);              \
  aB1 = *(const float4*)(Ab + (size_t)srow * N_ + (T) * BK + sc0 + 4);          \
  if (tid < TOTB) sbB = *(const uint4*)(Bb + (size_t)bch * CHSTR                \
                          + (size_t)(cg0 + 2 * (T) + bcc) * 512 + bl2 * 8);
#define WRITE_A(BUF)                                                            \
  *(uint4*)&at[BUF][srow][sc0] = rne8(aA0, aA1);                                \
  if (tid < TOTB) *(uint4*)&bt[BUF][bcc][bch][bl2][0] = sbA;
#define WRITE_B(BUF)                                                            \
  *(uint4*)&at[BUF][srow][sc0] = rne8(aB0, aB1);                                \
  if (tid < TOTB) *(uint4*)&bt[BUF][bcc][bch][bl2][0] = sbB;

  // ---- prologue: tiles 0 (set A) and 1 (set B) in flight; write tile 0 ----
  ISSUE_A(0)
  ISSUE_B(1)
  WRITE_A(0)                                   // counted wait: only set A's loads
  __syncthreads();

  f32x4 acc[NTW];
#pragma unroll
  for (int c = 0; c < NTW; ++c) acc[c] = (f32x4){0.f, 0.f, 0.f, 0.f};

#define COMPUTE(BUF)                                                            \
  _Pragma("unroll")                                                             \
  for (int c = 0; c < 2; ++c) {                                                 \
    short8 av = *(const short8*)&at[BUF][rg * 16 + (lane & 15)]                 \
                                  [c * 32 + (lane >> 4) * 8];                   \
    _Pragma("unroll")                                                           \
    for (int j = 0; j < NTW; ++j) {                                             \
      short8 bv = *(const short8*)&bt[BUF][c][cb + j][lane][0];                 \
      acc[j] = __builtin_amdgcn_mfma_f32_16x16x32_bf16(av, bv, acc[j], 0, 0, 0);\
    }                                                                           \
  }

  for (int tt = 0; tt < NTILE; tt += 2) {
    // --- even iteration t = tt: compute buf0; refill set A with tile tt+2 ---
    if (tt + 2 < NTILE) {
      ISSUE_A(tt + 2)
      __builtin_amdgcn_sched_barrier(0);       // pin: loads must not sink
    }
    COMPUTE(0)
    WRITE_B(1)                                 // tile tt+1 (issued last iter)
    __syncthreads();
    // --- odd iteration t = tt+1: compute buf1; refill set B with tile tt+3 ---
    if (tt + 3 < NTILE) {
      ISSUE_B(tt + 3)
      __builtin_amdgcn_sched_barrier(0);
    }
    COMPUTE(1)
    if (tt + 2 < NTILE) {
      WRITE_A(0)                               // tile tt+2 (issued last iter)
    }
    __syncthreads();
  }
#undef ISSUE_A
#undef ISSUE_B
#undef WRITE_A
#undef WRITE_B
#undef COMPUTE

  // C/D layout (m89): col = lane&15, row = (lane>>4)*4 + j
  const int orow = m0 + rg * 16 + ((lane >> 4) << 2);
  float* pp = P + ((size_t)(z * B_ + batch) * N_ + orow) * H + cb * 16 + (lane & 15);
#pragma unroll
  for (int j = 0; j < NTW; ++j)
#pragma unroll
    for (int jj = 0; jj < 4; ++jj)
      pp[(size_t)jj * H + j * 16] = acc[j][jj];
}

// -------- fused: h2 = relu(sum_z P2 + b2); dense partials vs Wd --------
__global__ __launch_bounds__(512) void k_densefuse(const float* __restrict__ P2,
                                                   const float* __restrict__ b2,
                                                   const float* __restrict__ Wd,
                                                   float* __restrict__ part) {
  constexpr int KC = 512;                  // 512 flat elems = 8 n-rows x 64 h
  __shared__ float hs[B_][KC];
  __shared__ float psum[B_][D1_];
  const int kc0 = blockIdx.x * KC;
  const int n0 = blockIdx.x * 8;
  const int tid = threadIdx.x;
  constexpr size_t TOT = (size_t)B_ * N_ * H2_;   // one z-slice
#pragma unroll
  for (int i = 0; i < 2; ++i) {            // reduce KS partials + bias + relu
    int q = tid + i * 512;
    int b = q >> 7, k4 = (q & 127) * 4;
    int nl = k4 >> 6, h = k4 & 63;
    size_t base = (((size_t)b * N_) + n0 + nl) * H2_ + h;
    float4 bv = *(const float4*)(b2 + h);
    float a0 = bv.x, a1 = bv.y, a2 = bv.z, a3 = bv.w;
#pragma unroll
    for (int zz = 0; zz < KS_; ++zz) {
      float4 v = *(const float4*)(P2 + base + (size_t)zz * TOT);
      a0 += v.x; a1 += v.y; a2 += v.z; a3 += v.w;
    }
    hs[b][k4 + 0] = fmaxf(a0, 0.f);
    hs[b][k4 + 1] = fmaxf(a1, 0.f);
    hs[b][k4 + 2] = fmaxf(a2, 0.f);
    hs[b][k4 + 3] = fmaxf(a3, 0.f);
  }
  __syncthreads();
  const int d0 = (tid & 31) * 4;           // 4 output cols
  const int b  = (tid >> 5) & 7;           // batch
  const int ks = tid >> 8;                 // in-block k-split (0/1)
  float a0 = 0.f, a1 = 0.f, a2 = 0.f, a3 = 0.f;
  const float* wp = Wd + ((size_t)kc0 + ks * 256) * D1_ + d0;
  const float* hp = &hs[b][ks * 256];
#pragma unroll 4
  for (int k = 0; k < 256; ++k) {
    float4 w = *(const float4*)(wp + (size_t)k * D1_);
    float h = hp[k];
    a0 = fmaf(h, w.x, a0); a1 = fmaf(h, w.y, a1);
    a2 = fmaf(h, w.z, a2); a3 = fmaf(h, w.w, a3);
  }
  if (ks == 1) {
    psum[b][d0] = a0; psum[b][d0 + 1] = a1; psum[b][d0 + 2] = a2; psum[b][d0 + 3] = a3;
  }
  __syncthreads();
  if (ks == 0) {
    float* pp = part + ((size_t)blockIdx.x * B_ + b) * D1_ + d0;
    *(float4*)pp = make_float4(a0 + psum[b][d0], a1 + psum[b][d0 + 1],
                               a2 + psum[b][d0 + 2], a3 + psum[b][d0 + 3]);
  }
}

// -------- final: per-batch block reduces 256 dense partials + sigmoid --------
__global__ __launch_bounds__(512) void k_dense_final(const float* __restrict__ part,
                                                     const float* __restrict__ bd,
                                                     const float* __restrict__ Wo,
                                                     const float* __restrict__ bo,
                                                     float* __restrict__ out) {
  __shared__ float ps[512];
  __shared__ float hdv[D1_];
  const int b = blockIdx.x;
  const int tid = threadIdx.x;
  const int d = tid & 127, seg = tid >> 7;     // 4-way k-split over 256 chunks
  float s = 0.f;
  for (int i = seg * 64; i < seg * 64 + 64; ++i)
    s += part[(size_t)i * (B_ * D1_) + b * D1_ + d];
  ps[tid] = s;
  __syncthreads();
  if (seg == 0)
    hdv[d] = fmaxf(ps[d] + ps[128 + d] + ps[256 + d] + ps[384 + d] + bd[d], 0.f);
  __syncthreads();
  if (tid < 64) {
    float v = hdv[tid] * Wo[tid] + hdv[64 + tid] * Wo[64 + tid];
#pragma unroll
    for (int off = 32; off; off >>= 1) v += __shfl_down(v, off, 64);
    if (tid == 0) out[b] = 1.f / (1.f + expf(-(v + bo[0])));
  }
}

extern "C" void kernel_launch(void* const* d_in, const int* in_sizes, int n_in,
                              void* d_out, int out_size, void* d_ws, size_t ws_size,
                              hipStream_t stream) {
  const float* x  = (const float*)d_in[0];
  const float* a  = (const float*)d_in[1];
  const float* W1 = (const float*)d_in[2];
  const float* b1 = (const float*)d_in[3];
  const float* W2 = (const float*)d_in[4];
  const float* b2 = (const float*)d_in[5];
  const float* Wd = (const float*)d_in[6];
  const float* bd = (const float*)d_in[7];
  const float* Wo = (const float*)d_in[8];
  const float* bo = (const float*)d_in[9];
  float* out = (float*)d_out;

  // workspace (floats): total 3,145,728 floats = 12.6 MB
  //  [0, 2097152)          P: agemm partials KS=2 (H1 uses first 1M, H2 all 2M)
  //  [2097152, 2359296)    Bt1h (bf16, 512K u16)
  //  [2359296, 2883584)    Bt2h (bf16, 1M u16)
  //  [2883584, 3145728)    dpart (256*8*128)
  float* ws    = (float*)d_ws;
  float* P     = ws;
  u16*   Bt1h  = (u16*)(ws + 2097152);
  u16*   Bt2h  = (u16*)(ws + 2359296);
  float* dpart = ws + 2883584;

  k_xw1cvt<<<dim3(N_ / 64, B_), 256, 0, stream>>>(x, W1, Bt1h);
  k_agemm_mfma<H1_><<<(N_ / 64) * B_ * KS_, 512, 0, stream>>>(a, Bt1h, P);
  k_l1fuse<<<dim3(N_ / 64, B_), 256, 0, stream>>>(P, b1, W2, Bt2h);
  k_agemm_mfma<H2_><<<(N_ / 64) * B_ * KS_, 512, 0, stream>>>(a, Bt2h, P);
  k_densefuse<<<(N_ * H2_) / 512, 512, 0, stream>>>(P, b2, Wd, dpart);
  k_dense_final<<<B_, 512, 0, stream>>>(dpart, bd, Wo, bo, out);
}

// Round 22
// 96.949 us; speedup vs baseline: 1.2437x; 1.0151x over previous
//
#include <hip/hip_runtime.h>
#include <math.h>

#define B_  8
#define N_  2048
#define F_  128
#define H1_ 32
#define H2_ 64
#define D1_ 128
#define KS_ 2            // K-split factor for the A-GEMMs
#define KSEG_ (N_ / KS_) // 1024 K per block

typedef unsigned short u16;
typedef unsigned int   u32;
typedef __attribute__((ext_vector_type(8))) short short8;  // 8 bf16 (4 VGPRs)
typedef __attribute__((ext_vector_type(4))) float f32x4;

// ---- round-to-nearest-even fp32 -> bf16 ----
__device__ __forceinline__ u16 rne1(float e) {
  u32 u = __float_as_uint(e);
  return (u16)((u + 0x7FFFu + ((u >> 16) & 1u)) >> 16);
}
__device__ __forceinline__ u32 rne2(float e0, float e1) {
  u32 u0 = __float_as_uint(e0), u1 = __float_as_uint(e1);
  u0 = (u0 + 0x7FFFu + ((u0 >> 16) & 1u)) >> 16;
  u1 = (u1 + 0x7FFFu + ((u1 >> 16) & 1u)) & 0xFFFF0000u;
  return u0 | u1;
}
__device__ __forceinline__ uint4 rne8(const float4 a, const float4 b) {
  return make_uint4(rne2(a.x, a.y), rne2(a.z, a.w), rne2(b.x, b.y), rne2(b.z, b.w));
}
// ---- bf16 (u16) -> fp32 ----
__device__ __forceinline__ float bflo(u32 w) { return __uint_as_float(w << 16); }
__device__ __forceinline__ float bfhi(u32 w) { return __uint_as_float(w & 0xFFFF0000u); }

// ---- pack a [64][LDST] fp32 LDS tile (rows = n, cols = h) into MFMA B-frag
// order (bf16 RNE). frag (b, ch, cg): 64 lanes x 8 bf16,
// lane = slot*16+cl holds B[k=cg*32+slot*8+i][col].
template<int H, int LDST>
__device__ __forceinline__ void pack_frags(const float* s, int b, int cgbase,
                                           u16* __restrict__ oh, int tid) {
  constexpr int CGRP = H / 16;
  constexpr int PASSES = H * 8 / 256;
#pragma unroll
  for (int p = 0; p < PASSES; ++p) {
    int q = tid + p * 256;
    int h = q >> 3, nn = (q & 7) * 8;           // 8 consecutive n for col h
    u32 hw[4];
#pragma unroll
    for (int j = 0; j < 4; ++j)
      hw[j] = rne2(s[(nn + 2 * j) * LDST + h], s[(nn + 2 * j + 1) * LDST + h]);
    int ch = h >> 4, cl = h & 15;
    int cg = cgbase + (nn >> 5);
    int lanep = ((nn >> 3) & 3) * 16 + cl;
    size_t o = ((((size_t)b * CGRP + ch) * (N_ / 32) + cg) * 64 + lanep) * 8;
    *(uint4*)(oh + o) = make_uint4(hw[0], hw[1], hw[2], hw[3]);
  }
}

// -------- fused: xw1 = x @ W1 (64-row tile), then pack (bf16) for agemm --------
__global__ __launch_bounds__(256) void k_xw1cvt(const float* __restrict__ x,
                                                const float* __restrict__ W1,
                                                u16* __restrict__ oh) {
  __shared__ float xs[64][F_];        // 32 KB
  __shared__ float w1s[F_ * H1_];     // 16 KB
  __shared__ float s[64][H1_ + 1];    // 8.4 KB
  const int b = blockIdx.y;
  const int n0 = blockIdx.x * 64;
  const int tid = threadIdx.x;
  const float* xp = x + ((size_t)b * N_ + n0) * F_;
#pragma unroll
  for (int i = 0; i < 8; ++i) {       // stage x tile: 8192 floats
    int q = tid + i * 256;
    int r = q >> 5, c4 = (q & 31) * 4;
    *(float4*)&xs[r][c4] = *(const float4*)(xp + (size_t)r * F_ + c4);
  }
#pragma unroll
  for (int i = 0; i < 4; ++i)         // stage W1: 4096 floats
    ((float4*)w1s)[tid + i * 256] = ((const float4*)W1)[tid + i * 256];
  __syncthreads();
  const int r = tid >> 2, c0 = (tid & 3) * 8;
  float acc[8] = {};
#pragma unroll
  for (int k = 0; k < F_; ++k) {
    float xv = xs[r][k];
#pragma unroll
    for (int j = 0; j < 8; ++j)
      acc[j] = fmaf(xv, w1s[k * H1_ + c0 + j], acc[j]);
  }
#pragma unroll
  for (int j = 0; j < 8; ++j) s[r][c0 + j] = acc[j];
  __syncthreads();
  pack_frags<H1_, H1_ + 1>(&s[0][0], b, blockIdx.x * 2, oh, tid);
}

// -------- fused: h1 = relu(sum_z P1 + b1); hw2 = h1 @ W2; pack (bf16) --------
// P1 is bf16 partials (u16), 4 per thread read as uint2.
__global__ __launch_bounds__(256) void k_l1fuse(const u16* __restrict__ P1,
                                                const float* __restrict__ b1,
                                                const float* __restrict__ W2,
                                                u16* __restrict__ oh) {
  __shared__ float h1s[64][H1_ + 1];   // 8.4 KB
  __shared__ float w2s[H1_ * H2_];     // 8 KB
  __shared__ float hw2s[64][H2_ + 1];  // 16.6 KB
  const int b = blockIdx.y;
  const int n0 = blockIdx.x * 64;
  const int tid = threadIdx.x;
  constexpr size_t TOT = (size_t)B_ * N_ * H1_;   // one z-slice (elements)
#pragma unroll
  for (int i = 0; i < 2; ++i) {        // reduce KS partials + bias + relu
    int q = tid + i * 256;
    int r = q >> 3, h4 = (q & 7) * 4;
    size_t base = (((size_t)b * N_) + n0 + r) * H1_ + h4;
    float4 bv = *(const float4*)(b1 + h4);
    float a0 = bv.x, a1 = bv.y, a2 = bv.z, a3 = bv.w;
#pragma unroll
    for (int zz = 0; zz < KS_; ++zz) {
      uint2 v = *(const uint2*)(P1 + base + (size_t)zz * TOT);
      a0 += bflo(v.x); a1 += bfhi(v.x);
      a2 += bflo(v.y); a3 += bfhi(v.y);
    }
    h1s[r][h4 + 0] = fmaxf(a0, 0.f);
    h1s[r][h4 + 1] = fmaxf(a1, 0.f);
    h1s[r][h4 + 2] = fmaxf(a2, 0.f);
    h1s[r][h4 + 3] = fmaxf(a3, 0.f);
  }
#pragma unroll
  for (int i = 0; i < 2; ++i)          // stage W2: 2048 floats
    ((float4*)w2s)[tid + i * 256] = ((const float4*)W2)[tid + i * 256];
  __syncthreads();
  const int r = tid >> 2, c0 = (tid & 3) * 16;
  float acc[16] = {};
#pragma unroll
  for (int k = 0; k < H1_; ++k) {
    float hv = h1s[r][k];
#pragma unroll
    for (int j = 0; j < 16; ++j)
      acc[j] = fmaf(hv, w2s[k * H2_ + c0 + j], acc[j]);
  }
#pragma unroll
  for (int j = 0; j < 16; ++j) hw2s[r][c0 + j] = acc[j];
  __syncthreads();
  pack_frags<H2_, H2_ + 1>(&hw2s[0][0], b, blockIdx.x * 2, oh, tid);
}

// -------- MFMA A-GEMM partials: bf16, A+B via LDS, 2-deep pipeline, KS=2 --------
// 1D grid 512 blocks x 8 waves with XCD-AWARE SWIZZLE (T1, r21-proven). P is
// written as bf16 partials (halves P traffic). Everything else = r21 config.
template<int H>
__global__ __launch_bounds__(512, 8) void k_agemm_mfma(const float* __restrict__ A,
                                                       const u16* __restrict__ Bph,
                                                       u16* __restrict__ P) {
  constexpr int NT = H / 16;
  constexpr int NTW = NT / 2;                  // col tiles per wave (H1:1, H2:2)
  constexpr int BK = 64;
  constexpr int NTILE = KSEG_ / BK;            // 16 (even)
  constexpr int CHSTR = (N_ / 32) * 512;       // u16 stride between colgroups
  constexpr int TOTB = 2 * NT * 64;            // B uint4 per tile (H1:256, H2:512)
  constexpr int NWG = (N_ / 64) * B_ * KS_;    // 512
  __shared__ u16 at[2][64][72];                // A tile bf16 (dbuf), 18.4 KB
  __shared__ u16 bt[2][2][NT][64][8];          // B frags (dbuf): H2 16 KB, H1 8 KB

  // XCD-aware bijective swizzle: same-XCD blocks take contiguous work ids
  const int swz = (blockIdx.x & 7) * (NWG >> 3) + (blockIdx.x >> 3);
  const int m0 = (swz & 31) * 64;              // m-tile (fastest)
  const int batch = (swz >> 5) & 7;
  const int z = swz >> 8;

  const int tid = threadIdx.x;
  const int lane = tid & 63;
  const int wave = tid >> 6;
  const int rg = wave & 3;                     // row-group
  const int cb = (wave >> 2) * NTW;            // col-tile base

  const float* Ab = A + (size_t)batch * N_ * N_ + (size_t)m0 * N_ + (size_t)z * KSEG_;
  const int srow = tid >> 3, sc0 = (tid & 7) * 8;   // A staging: eighth-row each

  const int cg0 = z * (KSEG_ / 32);            // first 32-chunk of this K segment
  const u16* Bb = Bph + (size_t)batch * NT * CHSTR;
  const int bseg = tid >> 6, bl2 = tid & 63;
  const int bcc = bseg / NT, bch = bseg % NT;  // valid when tid < TOTB

  // named regsets (A holds even tiles, B holds odd tiles)
  float4 aA0, aA1, aB0, aB1;
  uint4  sbA, sbB;

#define ISSUE_A(T)                                                              \
  aA0 = *(const float4*)(Ab + (size_t)srow * N_ + (T) * BK + sc0);              \
  aA1 = *(const float4*)(Ab + (size_t)srow * N_ + (T) * BK + sc0 + 4);          \
  if (tid < TOTB) sbA = *(const uint4*)(Bb + (size_t)bch * CHSTR                \
                          + (size_t)(cg0 + 2 * (T) + bcc) * 512 + bl2 * 8);
#define ISSUE_B(T)                                                              \
  aB0 = *(const float4*)(Ab + (size_t)srow * N_ + (T) * BK + sc0);              \
  aB1 = *(const float4*)(Ab + (size_t)srow * N_ + (T) * BK + sc0 + 4);          \
  if (tid < TOTB) sbB = *(const uint4*)(Bb + (size_t)bch * CHSTR                \
                          + (size_t)(cg0 + 2 * (T) + bcc) * 512 + bl2 * 8);
#define WRITE_A(BUF)                                                            \
  *(uint4*)&at[BUF][srow][sc0] = rne8(aA0, aA1);                                \
  if (tid < TOTB) *(uint4*)&bt[BUF][bcc][bch][bl2][0] = sbA;
#define WRITE_B(BUF)                                                            \
  *(uint4*)&at[BUF][srow][sc0] = rne8(aB0, aB1);                                \
  if (tid < TOTB) *(uint4*)&bt[BUF][bcc][bch][bl2][0] = sbB;

  // ---- prologue: tiles 0 (set A) and 1 (set B) in flight; write tile 0 ----
  ISSUE_A(0)
  ISSUE_B(1)
  WRITE_A(0)                                   // counted wait: only set A's loads
  __syncthreads();

  f32x4 acc[NTW];
#pragma unroll
  for (int c = 0; c < NTW; ++c) acc[c] = (f32x4){0.f, 0.f, 0.f, 0.f};

#define COMPUTE(BUF)                                                            \
  _Pragma("unroll")                                                             \
  for (int c = 0; c < 2; ++c) {                                                 \
    short8 av = *(const short8*)&at[BUF][rg * 16 + (lane & 15)]                 \
                                  [c * 32 + (lane >> 4) * 8];                   \
    _Pragma("unroll")                                                           \
    for (int j = 0; j < NTW; ++j) {                                             \
      short8 bv = *(const short8*)&bt[BUF][c][cb + j][lane][0];                 \
      acc[j] = __builtin_amdgcn_mfma_f32_16x16x32_bf16(av, bv, acc[j], 0, 0, 0);\
    }                                                                           \
  }

  for (int tt = 0; tt < NTILE; tt += 2) {
    // --- even iteration t = tt: compute buf0; refill set A with tile tt+2 ---
    if (tt + 2 < NTILE) {
      ISSUE_A(tt + 2)
      __builtin_amdgcn_sched_barrier(0);       // pin: loads must not sink
    }
    COMPUTE(0)
    WRITE_B(1)                                 // tile tt+1 (issued last iter)
    __syncthreads();
    // --- odd iteration t = tt+1: compute buf1; refill set B with tile tt+3 ---
    if (tt + 3 < NTILE) {
      ISSUE_B(tt + 3)
      __builtin_amdgcn_sched_barrier(0);
    }
    COMPUTE(1)
    if (tt + 2 < NTILE) {
      WRITE_A(0)                               // tile tt+2 (issued last iter)
    }
    __syncthreads();
  }
#undef ISSUE_A
#undef ISSUE_B
#undef WRITE_A
#undef WRITE_B
#undef COMPUTE

  // C/D layout (m89): col = lane&15, row = (lane>>4)*4 + j; write bf16 partials
  const int orow = m0 + rg * 16 + ((lane >> 4) << 2);
  u16* pp = P + ((size_t)(z * B_ + batch) * N_ + orow) * H + cb * 16 + (lane & 15);
#pragma unroll
  for (int j = 0; j < NTW; ++j)
#pragma unroll
    for (int jj = 0; jj < 4; ++jj)
      pp[(size_t)jj * H + j * 16] = rne1(acc[j][jj]);
}

// -------- fused: h2 = relu(sum_z P2 + b2); dense partials vs Wd --------
// P2 is bf16 partials (u16).
__global__ __launch_bounds__(512) void k_densefuse(const u16* __restrict__ P2,
                                                   const float* __restrict__ b2,
                                                   const float* __restrict__ Wd,
                                                   float* __restrict__ part) {
  constexpr int KC = 512;                  // 512 flat elems = 8 n-rows x 64 h
  __shared__ float hs[B_][KC];
  __shared__ float psum[B_][D1_];
  const int kc0 = blockIdx.x * KC;
  const int n0 = blockIdx.x * 8;
  const int tid = threadIdx.x;
  constexpr size_t TOT = (size_t)B_ * N_ * H2_;   // one z-slice (elements)
#pragma unroll
  for (int i = 0; i < 2; ++i) {            // reduce KS partials + bias + relu
    int q = tid + i * 512;
    int b = q >> 7, k4 = (q & 127) * 4;
    int nl = k4 >> 6, h = k4 & 63;
    size_t base = (((size_t)b * N_) + n0 + nl) * H2_ + h;
    float4 bv = *(const float4*)(b2 + h);
    float a0 = bv.x, a1 = bv.y, a2 = bv.z, a3 = bv.w;
#pragma unroll
    for (int zz = 0; zz < KS_; ++zz) {
      uint2 v = *(const uint2*)(P2 + base + (size_t)zz * TOT);
      a0 += bflo(v.x); a1 += bfhi(v.x);
      a2 += bflo(v.y); a3 += bfhi(v.y);
    }
    hs[b][k4 + 0] = fmaxf(a0, 0.f);
    hs[b][k4 + 1] = fmaxf(a1, 0.f);
    hs[b][k4 + 2] = fmaxf(a2, 0.f);
    hs[b][k4 + 3] = fmaxf(a3, 0.f);
  }
  __syncthreads();
  const int d0 = (tid & 31) * 4;           // 4 output cols
  const int b  = (tid >> 5) & 7;           // batch
  const int ks = tid >> 8;                 // in-block k-split (0/1)
  float a0 = 0.f, a1 = 0.f, a2 = 0.f, a3 = 0.f;
  const float* wp = Wd + ((size_t)kc0 + ks * 256) * D1_ + d0;
  const float* hp = &hs[b][ks * 256];
#pragma unroll 4
  for (int k = 0; k < 256; ++k) {
    float4 w = *(const float4*)(wp + (size_t)k * D1_);
    float h = hp[k];
    a0 = fmaf(h, w.x, a0); a1 = fmaf(h, w.y, a1);
    a2 = fmaf(h, w.z, a2); a3 = fmaf(h, w.w, a3);
  }
  if (ks == 1) {
    psum[b][d0] = a0; psum[b][d0 + 1] = a1; psum[b][d0 + 2] = a2; psum[b][d0 + 3] = a3;
  }
  __syncthreads();
  if (ks == 0) {
    float* pp = part + ((size_t)blockIdx.x * B_ + b) * D1_ + d0;
    *(float4*)pp = make_float4(a0 + psum[b][d0], a1 + psum[b][d0 + 1],
                               a2 + psum[b][d0 + 2], a3 + psum[b][d0 + 3]);
  }
}

// -------- final: per-batch block reduces 256 dense partials + sigmoid --------
__global__ __launch_bounds__(512) void k_dense_final(const float* __restrict__ part,
                                                     const float* __restrict__ bd,
                                                     const float* __restrict__ Wo,
                                                     const float* __restrict__ bo,
                                                     float* __restrict__ out) {
  __shared__ float ps[512];
  __shared__ float hdv[D1_];
  const int b = blockIdx.x;
  const int tid = threadIdx.x;
  const int d = tid & 127, seg = tid >> 7;     // 4-way k-split over 256 chunks
  float s = 0.f;
  for (int i = seg * 64; i < seg * 64 + 64; ++i)
    s += part[(size_t)i * (B_ * D1_) + b * D1_ + d];
  ps[tid] = s;
  __syncthreads();
  if (seg == 0)
    hdv[d] = fmaxf(ps[d] + ps[128 + d] + ps[256 + d] + ps[384 + d] + bd[d], 0.f);
  __syncthreads();
  if (tid < 64) {
    float v = hdv[tid] * Wo[tid] + hdv[64 + tid] * Wo[64 + tid];
#pragma unroll
    for (int off = 32; off; off >>= 1) v += __shfl_down(v, off, 64);
    if (tid == 0) out[b] = 1.f / (1.f + expf(-(v + bo[0])));
  }
}

extern "C" void kernel_launch(void* const* d_in, const int* in_sizes, int n_in,
                              void* d_out, int out_size, void* d_ws, size_t ws_size,
                              hipStream_t stream) {
  const float* x  = (const float*)d_in[0];
  const float* a  = (const float*)d_in[1];
  const float* W1 = (const float*)d_in[2];
  const float* b1 = (const float*)d_in[3];
  const float* W2 = (const float*)d_in[4];
  const float* b2 = (const float*)d_in[5];
  const float* Wd = (const float*)d_in[6];
  const float* bd = (const float*)d_in[7];
  const float* Wo = (const float*)d_in[8];
  const float* bo = (const float*)d_in[9];
  float* out = (float*)d_out;

  // workspace (floats): total 2,097,152 floats = 8.4 MB
  //  [0, 1048576)          P: bf16 agemm partials KS=2 (u16; H2 uses all 2M u16)
  //  [1048576, 1310720)    Bt1h (bf16, 512K u16)
  //  [1310720, 1835008)    Bt2h (bf16, 1M u16)
  //  [1835008, 2097152)    dpart (256*8*128 fp32)
  float* ws    = (float*)d_ws;
  u16*   P     = (u16*)ws;
  u16*   Bt1h  = (u16*)(ws + 1048576);
  u16*   Bt2h  = (u16*)(ws + 1310720);
  float* dpart = ws + 1835008;

  k_xw1cvt<<<dim3(N_ / 64, B_), 256, 0, stream>>>(x, W1, Bt1h);
  k_agemm_mfma<H1_><<<(N_ / 64) * B_ * KS_, 512, 0, stream>>>(a, Bt1h, P);
  k_l1fuse<<<dim3(N_ / 64, B_), 256, 0, stream>>>(P, b1, W2, Bt2h);
  k_agemm_mfma<H2_><<<(N_ / 64) * B_ * KS_, 512, 0, stream>>>(a, Bt2h, P);
  k_densefuse<<<(N_ * H2_) / 512, 512, 0, stream>>>(P, b2, Wd, dpart);
  k_dense_final<<<B_, 512, 0, stream>>>(dpart, bd, Wo, bo, out);
}